// Round 10
// baseline (413.293 us; speedup 1.0000x reference)
//
#include <hip/hip_runtime.h>
#include <stdint.h>

#define DI __device__ __forceinline__

static constexpr int B_   = 512;
static constexpr int N3_  = 381;

typedef short bf16x8 __attribute__((ext_vector_type(8)));
typedef float f32x4  __attribute__((ext_vector_type(4)));

DI float bf2f(uint32_t u) { union { uint32_t i; float f; } v; v.i = u << 16; return v.f; }
DI uint16_t f2bf(float f) {
  union { float f; uint32_t i; } v; v.f = f;
  uint32_t x = v.i;
  return (uint16_t)((x + 0x7fffu + ((x >> 16) & 1u)) >> 16);
}
DI void unpack8(uint4 u, float* v) {
  v[0] = bf2f(u.x & 0xffffu); v[1] = bf2f(u.x >> 16);
  v[2] = bf2f(u.y & 0xffffu); v[3] = bf2f(u.y >> 16);
  v[4] = bf2f(u.z & 0xffffu); v[5] = bf2f(u.z >> 16);
  v[6] = bf2f(u.w & 0xffffu); v[7] = bf2f(u.w >> 16);
}

DI void ldsload16(const uint16_t* g, uint16_t* l) {
  __builtin_amdgcn_global_load_lds((const __attribute__((address_space(1))) void*)g,
                                   (__attribute__((address_space(3))) void*)l,
                                   16, 0, 0);
}

// ---------------- fused prep: probe + transpose + all conversions ------------
struct PrepArgs {
  const void* trees; const void* w1; const void* w2; const void* w3; const void* gw1;
  const void* b1; const void* b2; const void* b3; const void* gb1;
  const void* gw2; const void* gb2;
  const void* rw1; const void* rb1; const void* rw2; const void* rb2;
  const void* rw3; const void* rb3;
  uint16_t* treesT; uint16_t* W1b; uint16_t* W2b; uint16_t* W3b; uint16_t* GW1b;
  float* b1f; float* b2f; float* b3f; float* gb1f; float* gw2f; float* gb2f;
  float* rw1f; float* rb1f; float* rw2f; float* rb2f; float* rw3f; float* rb3f;
  int* flagp; float* statsAcc;
};

static constexpr int PREP_TRANS_END = 3584;   // 7 * 512 transpose blocks
static constexpr int PREP_W1_END    = 3840;
static constexpr int PREP_W2_END    = 4352;
static constexpr int PREP_W3_END    = 4608;
static constexpr int PREP_GW1_END   = 4640;
static constexpr int PREP_F32_END   = 4672;

DI void wcvt_range(const void* src, uint16_t* dst, int O, int C, int Cpad,
                   int isf32, int idx, int nb) {
  int Kpad = 3 * Cpad;
  int n = O * Kpad;
  int stride = nb * 256;
  for (int i = idx * 256 + (int)threadIdx.x; i < n; i += stride) {
    int o = i / Kpad, e = i - o * Kpad;
    int reg = e / Cpad, c = e - reg * Cpad;
    uint16_t v = 0;
    if (c < C) {
      int s = (o * C + c) * 3 + reg;
      v = isf32 ? f2bf(((const float*)src)[s]) : ((const uint16_t*)src)[s];
    }
    dst[i] = v;
  }
}

DI void fcvt_range(const void* src, float* dst, int n, int isf32, int idx, int nb) {
  int stride = nb * 256;
  for (int i = idx * 256 + (int)threadIdx.x; i < n; i += stride)
    dst[i] = isf32 ? ((const float*)src)[i] : bf2f(((const uint16_t*)src)[i]);
}

__global__ __launch_bounds__(256)
void prep_kernel(PrepArgs a) {
  __shared__ int cnt;
  __shared__ uint16_t sX[32][130];

  const int id = blockIdx.x;
  const int tx = threadIdx.x;

  if (tx == 0) cnt = 0;
  __syncthreads();
  {
    const uint16_t* t16 = (const uint16_t*)a.trees;
    int local = 0;
    #pragma unroll
    for (int q = 0; q < 2; q++) {
      uint16_t u = t16[tx * 2 + q];
      int ex = (u >> 7) & 0xff;
      if (ex >= 110 && ex <= 133) local++;
    }
    atomicAdd(&cnt, local);
  }
  __syncthreads();
  const int isf32 = (cnt >= 450) ? 0 : 1;

  if (id == 0) {
    if (tx == 0) *a.flagp = isf32;
    #pragma unroll
    for (int q = 0; q < 8; q++) a.statsAcc[q * 256 + tx] = 0.f;
  }

  if (id < PREP_TRANS_END) {
    const int b = id / 7, c0 = (id % 7) * 32;
    const int cn = min(32, 200 - c0);
    if (isf32) {
      const float* src = (const float*)a.trees + ((size_t)b * 200 + c0) * 128;
      for (int t = tx; t < cn * 128; t += 256) {
        int c = t >> 7, m = t & 127;
        sX[c][m] = f2bf(src[c * 128 + m]);
      }
    } else {
      const uint32_t* src = (const uint32_t*)((const uint16_t*)a.trees + ((size_t)b * 200 + c0) * 128);
      for (int t = tx; t < cn * 64; t += 256) {
        int c = t >> 6, p = t & 63;
        ((uint32_t*)&sX[c][0])[p] = src[c * 64 + p];
      }
    }
    __syncthreads();
    uint32_t* out = (uint32_t*)(a.treesT + (size_t)b * 129 * 256 + c0);
    for (int p = tx; p < 129 * 16; p += 256) {
      int m = p >> 4, u = p & 15;
      int c = u * 2;
      uint32_t v = 0;
      if (m < 128) {
        uint16_t lo = (c     < cn) ? sX[c][m]     : (uint16_t)0;
        uint16_t hi = (c + 1 < cn) ? sX[c + 1][m] : (uint16_t)0;
        v = (uint32_t)lo | ((uint32_t)hi << 16);
      }
      out[(size_t)m * 128 + u] = v;
    }
  } else if (id < PREP_W1_END) {
    wcvt_range(a.w1, a.W1b, 512, 200, 256, isf32, id - PREP_TRANS_END, PREP_W1_END - PREP_TRANS_END);
  } else if (id < PREP_W2_END) {
    wcvt_range(a.w2, a.W2b, 512, 512, 512, isf32, id - PREP_W1_END, PREP_W2_END - PREP_W1_END);
  } else if (id < PREP_W3_END) {
    wcvt_range(a.w3, a.W3b, 256, 512, 512, isf32, id - PREP_W2_END, PREP_W3_END - PREP_W2_END);
  } else if (id < PREP_GW1_END) {
    int idx = id - PREP_W3_END, nb = PREP_GW1_END - PREP_W3_END;
    int stride = nb * 256;
    for (int i = idx * 256 + tx; i < 128 * 256; i += stride)
      a.GW1b[i] = isf32 ? f2bf(((const float*)a.gw1)[i]) : ((const uint16_t*)a.gw1)[i];
  } else {
    int idx = id - PREP_GW1_END, nb = PREP_F32_END - PREP_GW1_END;
    fcvt_range(a.rw1, a.rw1f, 128 * 512, isf32, idx, nb);
    fcvt_range(a.rw2, a.rw2f, 64 * 128, isf32, idx, nb);
    if (idx == 0) {
      fcvt_range(a.b1, a.b1f, 512, isf32, 0, 1);
      fcvt_range(a.b2, a.b2f, 512, isf32, 0, 1);
      fcvt_range(a.b3, a.b3f, 256, isf32, 0, 1);
      fcvt_range(a.gb1, a.gb1f, 128, isf32, 0, 1);
      fcvt_range(a.gw2, a.gw2f, 128, isf32, 0, 1);
      fcvt_range(a.gb2, a.gb2f, 1, isf32, 0, 1);
      fcvt_range(a.rb1, a.rb1f, 128, isf32, 0, 1);
      fcvt_range(a.rb2, a.rb2f, 64, isf32, 0, 1);
      fcvt_range(a.rw3, a.rw3f, 64, isf32, 0, 1);
      fcvt_range(a.rb3, a.rb3f, 1, isf32, 0, 1);
    }
  }
}

// ------ fused gather+GEMM (layers 1,2): 128x128 tile, 2x2 waves of 64x64 ----
// 1D grid nO*B_ (nO counts 128-wide o-tiles), XCD-swizzled.
__global__ __launch_bounds__(256, 4)
void gemm_kernel(const uint16_t* __restrict__ A,
                 const uint16_t* __restrict__ xT,
                 const int* __restrict__ idxg,
                 const float* __restrict__ bias,
                 uint16_t* __restrict__ Y,
                 int nO, int Cpad, int outRS,
                 float* __restrict__ statsAcc) {
  __shared__ __align__(16) uint16_t sA[128 * 64];
  __shared__ __align__(16) uint16_t sB[128 * 64];
  __shared__ float sBias[128];
  __shared__ int sIdx[384];
  __shared__ float2 sRed[256];

  const int id   = blockIdx.x;
  const int xcd  = id & 7;
  const int rest = id >> 3;
  const int ot   = rest % nO;
  const int b    = (rest / nO) * 8 + xcd;
  const int obase = ot * 128;
  const int O     = nO * 128;

  const int tx    = threadIdx.x;
  const int wave  = tx >> 6, lane = tx & 63;
  const int wj    = wave & 1, wo = wave >> 1;
  const int Kpad  = 3 * Cpad;

  for (int t = tx; t < N3_; t += 256) sIdx[t] = idxg[(size_t)b * N3_ + t];
  if (tx < 128) sBias[tx] = bias[obase + tx];
  __syncthreads();

  const uint16_t* Abase = A + (size_t)obase * Kpad;
  const uint16_t* Bbase = xT + (size_t)b * 129 * Cpad;

  const int srow = lane >> 3;
  const int schk = lane & 7;
  const int lm = lane & 15;
  const int kg = lane >> 4;

  f32x4 zero4 = {0.f, 0.f, 0.f, 0.f};
  f32x4 acc[4][4];
  #pragma unroll
  for (int i = 0; i < 4; i++)
    #pragma unroll
    for (int j = 0; j < 4; j++) acc[i][j] = zero4;

  for (int reg = 0; reg < 3; reg++) {
    int ridx[4];
    #pragma unroll
    for (int i = 0; i < 4; i++) {
      int r = wave * 8 + i * 32 + srow;
      ridx[i] = (r == 0) ? 128 : sIdx[3 * (r - 1) + reg];
    }
    for (int co = 0; co < Cpad; co += 64) {
      __syncthreads();
      #pragma unroll
      for (int i = 0; i < 4; i++) {
        int r  = wave * 8 + i * 32 + srow;
        int ca = schk ^ (r & 7);
        ldsload16(Abase + (size_t)r * Kpad + reg * Cpad + co + ca * 8,
                  &sA[(wave * 8 + i * 32) * 64]);
        ldsload16(Bbase + (size_t)ridx[i] * Cpad + co + ca * 8,
                  &sB[(wave * 8 + i * 32) * 64]);
      }
      __syncthreads();
      #pragma unroll
      for (int s = 0; s < 2; s++) {
        bf16x8 xv[4], wv[4];
        #pragma unroll
        for (int f = 0; f < 4; f++) {
          int rj = wj * 64 + f * 16 + lm;
          int cj = (s * 4 + kg) ^ (rj & 7);
          xv[f] = *(const bf16x8*)&sB[rj * 64 + cj * 8];
          int ro = wo * 64 + f * 16 + lm;
          int cw = (s * 4 + kg) ^ (ro & 7);
          wv[f] = *(const bf16x8*)&sA[ro * 64 + cw * 8];
        }
        #pragma unroll
        for (int fj = 0; fj < 4; fj++)
          #pragma unroll
          for (int fo = 0; fo < 4; fo++)
            acc[fj][fo] = __builtin_amdgcn_mfma_f32_16x16x32_bf16(xv[fj], wv[fo], acc[fj][fo], 0, 0, 0);
      }
    }
  }

  // epilogue: C rows = j, cols = o. bias, zero row j==0, stats, store yT.
  float s1 = 0.f, s2 = 0.f;
  #pragma unroll
  for (int fj = 0; fj < 4; fj++) {
    #pragma unroll
    for (int fo = 0; fo < 4; fo++) {
      int olocal = wo * 64 + fo * 16 + lm;
      float bo = sBias[olocal];
      #pragma unroll
      for (int r = 0; r < 4; r++) {
        int j = wj * 64 + fj * 16 + kg * 4 + r;
        float v = acc[fj][fo][r] + bo;
        if (j == 0) v = 0.f;
        s1 += v; s2 += v * v;
        Y[((size_t)b * outRS + j) * O + obase + olocal] = f2bf(v);
      }
    }
  }

  sRed[tx] = make_float2(s1, s2);
  __syncthreads();
  for (int s = 128; s > 0; s >>= 1) {
    if (tx < s) { sRed[tx].x += sRed[tx + s].x; sRed[tx].y += sRed[tx + s].y; }
    __syncthreads();
  }
  if (tx == 0) {
    atomicAdd(&statsAcc[b * 2],     sRed[0].x);
    atomicAdd(&statsAcc[b * 2 + 1], sRed[0].y);
  }
}

// ------- LN+ReLU in place on yT [B][129][512]; b from blockIdx --------------
__global__ __launch_bounds__(256)
void ln_relu_kernel(uint16_t* __restrict__ y, const float* __restrict__ statsAcc,
                    float count) {
  const int b    = blockIdx.x >> 2;
  const int part = blockIdx.x & 3;
  float s = statsAcc[b * 2], ss = statsAcc[b * 2 + 1];
  float mean = s / count;
  float var = fmaxf((ss - s * s / count) / (count - 1.0f), 0.f);
  float scale = 1.0f / (sqrtf(var) + 1e-5f);

  uint4* yb = (uint4*)y + (size_t)b * 8256;       // 129*64 uint4 per batch
  for (int i = part * 2064 + threadIdx.x; i < (part + 1) * 2064; i += 256) {
    int r = i >> 6;
    uint4 out;
    if (r == 128) {
      out = make_uint4(0, 0, 0, 0);
    } else {
      uint4 u = yb[i];
      float v[8]; unpack8(u, v);
      uint32_t rr[4];
      #pragma unroll
      for (int k = 0; k < 4; k++) {
        float a  = fmaxf((v[2 * k]     - mean) * scale, 0.f);
        float bb = fmaxf((v[2 * k + 1] - mean) * scale, 0.f);
        rr[k] = (uint32_t)f2bf(a) | ((uint32_t)f2bf(bb) << 16);
      }
      out = make_uint4(rr[0], rr[1], rr[2], rr[3]);
    }
    yb[i] = out;
  }
}

// ------ tail: layer-3 gemm (emb stays in LDS) + gate + softmax + pool + head
__global__ __launch_bounds__(256, 2)
void tail_kernel(const uint16_t* __restrict__ W3,      // [256][1536]
                 const uint16_t* __restrict__ xT,      // y2T [B][129][512]
                 const int* __restrict__ idxg,
                 const float* __restrict__ b3,
                 const uint16_t* __restrict__ gw1b,    // [128][256] bf16
                 const float* __restrict__ gb1,
                 const float* __restrict__ gw2, const float* __restrict__ gb2,
                 const float* __restrict__ rw1, const float* __restrict__ rb1,
                 const float* __restrict__ rw2, const float* __restrict__ rb2,
                 const float* __restrict__ rw3, const float* __restrict__ rb3,
                 void* __restrict__ dout, const int* __restrict__ flag) {
  __shared__ __align__(16) uint16_t sEmbF[4][128][64];   // 64 KB; aliases sA/sB
  __shared__ float sBias[256];
  __shared__ int sIdx[384];
  __shared__ float sRedG[4][128];
  __shared__ float sSm[128];
  __shared__ float sAttn[128];
  __shared__ float sPool4[4 * 256];
  __shared__ __align__(16) float sC[512];
  __shared__ __align__(16) float sH1[128];
  __shared__ float sH2[64];

  uint16_t* sA = &sEmbF[0][0][0];          // 256*64 shorts = 32 KB
  uint16_t* sB = sA + 256 * 64;            // 128*64 shorts = 16 KB

  const int b  = blockIdx.x;
  const int tx = threadIdx.x;
  const int wave = tx >> 6, lane = tx & 63;
  const int wj = wave & 1, wo = wave >> 1;
  const int lm = lane & 15, kg = lane >> 4;
  const int srow = lane >> 3, schk = lane & 7;
  const int Kpad = 1536, Cpad = 512;

  for (int t = tx; t < N3_; t += 256) sIdx[t] = idxg[(size_t)b * N3_ + t];
  sBias[tx] = b3[tx];
  __syncthreads();

  const uint16_t* Bbase = xT + (size_t)b * 129 * Cpad;

  // ---- phase 1: layer-3 GEMM (128j x 256o), acc in regs ----
  f32x4 zero4 = {0.f, 0.f, 0.f, 0.f};
  f32x4 acc[4][8];
  #pragma unroll
  for (int i = 0; i < 4; i++)
    #pragma unroll
    for (int j = 0; j < 8; j++) acc[i][j] = zero4;

  for (int reg = 0; reg < 3; reg++) {
    int ridx[4];
    #pragma unroll
    for (int i = 0; i < 4; i++) {
      int r = i * 32 + wave * 8 + srow;
      ridx[i] = (r == 0) ? 128 : sIdx[3 * (r - 1) + reg];
    }
    for (int co = 0; co < Cpad; co += 64) {
      __syncthreads();
      #pragma unroll
      for (int i = 0; i < 8; i++) {
        int r  = i * 32 + wave * 8 + srow;
        int ca = schk ^ (r & 7);
        ldsload16(W3 + (size_t)r * Kpad + reg * Cpad + co + ca * 8,
                  &sA[(i * 32 + wave * 8) * 64]);
      }
      #pragma unroll
      for (int i = 0; i < 4; i++) {
        int r  = i * 32 + wave * 8 + srow;
        int ca = schk ^ (r & 7);
        ldsload16(Bbase + (size_t)ridx[i] * Cpad + co + ca * 8,
                  &sB[(i * 32 + wave * 8) * 64]);
      }
      __syncthreads();
      #pragma unroll
      for (int s = 0; s < 2; s++) {
        bf16x8 xv[4], wv[8];
        #pragma unroll
        for (int f = 0; f < 4; f++) {
          int rj = wj * 64 + f * 16 + lm;
          int cj = (s * 4 + kg) ^ (rj & 7);
          xv[f] = *(const bf16x8*)&sB[rj * 64 + cj * 8];
        }
        #pragma unroll
        for (int f = 0; f < 8; f++) {
          int ro = wo * 128 + f * 16 + lm;
          int cw = (s * 4 + kg) ^ (ro & 7);
          wv[f] = *(const bf16x8*)&sA[ro * 64 + cw * 8];
        }
        #pragma unroll
        for (int fj = 0; fj < 4; fj++)
          #pragma unroll
          for (int fo = 0; fo < 8; fo++)
            acc[fj][fo] = __builtin_amdgcn_mfma_f32_16x16x32_bf16(xv[fj], wv[fo], acc[fj][fo], 0, 0, 0);
      }
    }
  }

  // ---- phase 2: epilogue -> LDS emb in swizzled layout ----
  __syncthreads();   // sA/sB dead; reuse as sEmbF
  #pragma unroll
  for (int fj = 0; fj < 4; fj++) {
    #pragma unroll
    for (int fo = 0; fo < 8; fo++) {
      int olocal = wo * 128 + fo * 16 + lm;
      int sec = olocal >> 6, oc = olocal & 63;
      float bo = sBias[olocal];
      #pragma unroll
      for (int r = 0; r < 4; r++) {
        int j = wj * 64 + fj * 16 + kg * 4 + r;
        float v = acc[fj][fo][r] + bo;
        if (j == 0) v = 0.f;
        int chunk = (oc >> 3) ^ (j & 7);
        sEmbF[sec][j][chunk * 8 + (oc & 7)] = f2bf(v);
      }
    }
  }
  __syncthreads();

  // ---- phase 3: gate1 MFMA from LDS emb ----
  const int h0 = wave * 32;
  f32x4 acc2[2][8];
  #pragma unroll
  for (int i = 0; i < 2; i++)
    #pragma unroll
    for (int t = 0; t < 8; t++) acc2[i][t] = zero4;

  #pragma unroll
  for (int s4 = 0; s4 < 4; s4++) {
    #pragma unroll
    for (int s = 0; s < 2; s++) {
      bf16x8 a0 = *(const bf16x8*)(gw1b + (size_t)(h0 + lm) * 256 + s4 * 64 + s * 32 + kg * 8);
      bf16x8 a1 = *(const bf16x8*)(gw1b + (size_t)(h0 + 16 + lm) * 256 + s4 * 64 + s * 32 + kg * 8);
      #pragma unroll
      for (int t = 0; t < 8; t++) {
        int rn = t * 16 + lm;
        int cn = (s * 4 + kg) ^ (rn & 7);
        bf16x8 bv = *(const bf16x8*)&sEmbF[s4][rn][cn * 8];
        acc2[0][t] = __builtin_amdgcn_mfma_f32_16x16x32_bf16(a0, bv, acc2[0][t], 0, 0, 0);
        acc2[1][t] = __builtin_amdgcn_mfma_f32_16x16x32_bf16(a1, bv, acc2[1][t], 0, 0, 0);
      }
    }
  }

  float gb[2][4], gv[2][4];
  #pragma unroll
  for (int ht = 0; ht < 2; ht++)
    #pragma unroll
    for (int r = 0; r < 4; r++) {
      int h = h0 + ht * 16 + kg * 4 + r;
      gb[ht][r] = gb1[h]; gv[ht][r] = gw2[h];
    }
  float p[8];
  #pragma unroll
  for (int t = 0; t < 8; t++) {
    float s = 0.f;
    #pragma unroll
    for (int ht = 0; ht < 2; ht++)
      #pragma unroll
      for (int r = 0; r < 4; r++)
        s += fmaxf(acc2[ht][t][r] + gb[ht][r], 0.f) * gv[ht][r];
    s += __shfl_xor(s, 16);
    s += __shfl_xor(s, 32);
    p[t] = s;
  }
  if (lane < 16) {
    #pragma unroll
    for (int t = 0; t < 8; t++) sRedG[wave][t * 16 + lane] = p[t];
  }
  __syncthreads();

  // ---- softmax over m ----
  float e = 0.f;
  if (tx < 128) {
    float v = sRedG[0][tx] + sRedG[1][tx] + sRedG[2][tx] + sRedG[3][tx] + gb2[0];
    sSm[tx] = v;
    sAttn[tx] = v;
  }
  __syncthreads();
  for (int s = 64; s > 0; s >>= 1) {
    if (tx < s) sSm[tx] = fmaxf(sSm[tx], sSm[tx + s]);
    __syncthreads();
  }
  float mx = sSm[0];
  __syncthreads();
  if (tx < 128) { e = expf(sAttn[tx] - mx); sSm[tx] = e; }
  __syncthreads();
  for (int s = 64; s > 0; s >>= 1) {
    if (tx < s) sSm[tx] += sSm[tx + s];
    __syncthreads();
  }
  float denom = sSm[0];
  __syncthreads();
  if (tx < 128) sAttn[tx] = e / denom;
  __syncthreads();

  // ---- pool from LDS emb: wave covers 32 m rows; lane -> f pairs ----
  {
    const int f0 = 2 * lane;           // 0..126
    const int sec0 = f0 >> 6, oc0 = f0 & 63;
    const int sec2 = sec0 + 2;         // f+128
    float pl00 = 0.f, pl01 = 0.f, pl10 = 0.f, pl11 = 0.f;
    const int mw = wave * 32;
    for (int mi = 0; mi < 32; mi++) {
      int m = mw + mi;
      float a = sAttn[m];
      int idx = ((oc0 >> 3) ^ (m & 7)) * 8 + (oc0 & 7);
      uint32_t u0 = *(const uint32_t*)&sEmbF[sec0][m][idx];
      uint32_t u1 = *(const uint32_t*)&sEmbF[sec2][m][idx];
      pl00 = fmaf(a, bf2f(u0 & 0xffffu), pl00);
      pl01 = fmaf(a, bf2f(u0 >> 16),     pl01);
      pl10 = fmaf(a, bf2f(u1 & 0xffffu), pl10);
      pl11 = fmaf(a, bf2f(u1 >> 16),     pl11);
    }
    sPool4[wave * 256 + lane * 2]           = pl00;
    sPool4[wave * 256 + lane * 2 + 1]       = pl01;
    sPool4[wave * 256 + 128 + lane * 2]     = pl10;
    sPool4[wave * 256 + 128 + lane * 2 + 1] = pl11;
  }
  __syncthreads();

  float pool = sPool4[tx] + sPool4[256 + tx] + sPool4[512 + tx] + sPool4[768 + tx];
  float root;
  {
    int sec = tx >> 6, oc = tx & 63;
    int idx = ((oc >> 3) ^ 1) * 8 + (oc & 7);
    root = bf2f(sEmbF[sec][1][idx]);
  }
  sC[tx]       = root;
  sC[256 + tx] = pool;

  const int isf32 = (*flag != 0);
  if (!isf32) {
    uint16_t* o = ((uint16_t*)dout) + 512;
    o[b * 512 + tx]       = f2bf(root);
    o[b * 512 + 256 + tx] = f2bf(pool);
  } else {
    float* o = ((float*)dout) + 512;
    o[b * 512 + tx]       = root;
    o[b * 512 + 256 + tx] = pool;
  }
  __syncthreads();

  // ---- fused MLP head ----
  if (tx < 128) {
    float a = rb1[tx];
    const float4* wr = (const float4*)(rw1 + (size_t)tx * 512);
    for (int i = 0; i < 128; i++) {
      float4 w4 = wr[i];
      float4 c4 = *(const float4*)&sC[i * 4];
      a = fmaf(w4.x, c4.x, a); a = fmaf(w4.y, c4.y, a);
      a = fmaf(w4.z, c4.z, a); a = fmaf(w4.w, c4.w, a);
    }
    sH1[tx] = fmaxf(a, 0.f);
  }
  __syncthreads();
  if (tx < 64) {
    float a2 = rb2[tx];
    const float4* wr2 = (const float4*)(rw2 + (size_t)tx * 128);
    for (int i = 0; i < 32; i++) {
      float4 w4 = wr2[i];
      float4 h4 = *(const float4*)&sH1[i * 4];
      a2 = fmaf(w4.x, h4.x, a2); a2 = fmaf(w4.y, h4.y, a2);
      a2 = fmaf(w4.z, h4.z, a2); a2 = fmaf(w4.w, h4.w, a2);
    }
    sH2[tx] = fmaxf(a2, 0.f);
  }
  __syncthreads();
  if (tx < 64) {
    float pv = sH2[tx] * rw3[tx];
    for (int off = 32; off > 0; off >>= 1) pv += __shfl_down(pv, off);
    if (tx == 0) {
      float o = pv + rb3[0];
      if (!isf32) ((uint16_t*)dout)[b] = f2bf(o);
      else        ((float*)dout)[b]    = o;
    }
  }
}

// ---------------- launch -----------------------------------------------------
extern "C" void kernel_launch(void* const* d_in, const int* in_sizes, int n_in,
                              void* d_out, int out_size, void* d_ws, size_t ws_size,
                              hipStream_t stream) {
  const void* trees   = d_in[0];
  const int*  indexes = (const int*)d_in[1];

  char* ws = (char*)d_ws;
  size_t off = 0;
  auto alloc = [&](size_t bytes) -> char* {
    char* p = ws + off;
    off += (bytes + 255) & ~(size_t)255;
    return p;
  };

  int*   flagp    = (int*)alloc(256);
  float* statsAcc = (float*)alloc(4 * B_ * sizeof(float));
  float* b1f = (float*)alloc(512 * 4);
  float* b2f = (float*)alloc(512 * 4);
  float* b3f = (float*)alloc(256 * 4);
  float* gb1f = (float*)alloc(128 * 4);
  float* gw2f = (float*)alloc(128 * 4);
  float* gb2f = (float*)alloc(4);
  float* rw1f = (float*)alloc(128 * 512 * 4);
  float* rb1f = (float*)alloc(128 * 4);
  float* rw2f = (float*)alloc(64 * 128 * 4);
  float* rb2f = (float*)alloc(64 * 4);
  float* rw3f = (float*)alloc(64 * 4);
  float* rb3f = (float*)alloc(4);
  uint16_t* W1b  = (uint16_t*)alloc((size_t)512 * 768 * 2);
  uint16_t* W2b  = (uint16_t*)alloc((size_t)512 * 1536 * 2);
  uint16_t* W3b  = (uint16_t*)alloc((size_t)256 * 1536 * 2);
  uint16_t* GW1b = (uint16_t*)alloc((size_t)128 * 256 * 2);
  uint16_t* bufA = (uint16_t*)alloc((size_t)B_ * 129 * 512 * 2);   // y1T
  uint16_t* bufB = (uint16_t*)alloc((size_t)B_ * 129 * 512 * 2);   // treesT, later y2T

  uint16_t* treesT = bufB;            // [B][129][256]
  uint16_t* y1T    = bufA;            // [B][129][512]
  uint16_t* y2T    = bufB;            // [B][129][512]

  PrepArgs pa;
  pa.trees = trees;
  pa.w1 = d_in[2];  pa.b1 = d_in[3];
  pa.w2 = d_in[4];  pa.b2 = d_in[5];
  pa.w3 = d_in[6];  pa.b3 = d_in[7];
  pa.gw1 = d_in[8]; pa.gb1 = d_in[9];
  pa.gw2 = d_in[10]; pa.gb2 = d_in[11];
  pa.rw1 = d_in[12]; pa.rb1 = d_in[13];
  pa.rw2 = d_in[14]; pa.rb2 = d_in[15];
  pa.rw3 = d_in[16]; pa.rb3 = d_in[17];
  pa.treesT = treesT; pa.W1b = W1b; pa.W2b = W2b; pa.W3b = W3b; pa.GW1b = GW1b;
  pa.b1f = b1f; pa.b2f = b2f; pa.b3f = b3f; pa.gb1f = gb1f; pa.gw2f = gw2f; pa.gb2f = gb2f;
  pa.rw1f = rw1f; pa.rb1f = rb1f; pa.rw2f = rw2f; pa.rb2f = rb2f; pa.rw3f = rw3f; pa.rb3f = rb3f;
  pa.flagp = flagp; pa.statsAcc = statsAcc;

  prep_kernel<<<PREP_F32_END, 256, 0, stream>>>(pa);

  // ---- layer 1: Cpad=256 (K=768), in treesT, out y1T ----
  gemm_kernel<<<4 * B_, 256, 0, stream>>>(
      W1b, treesT, indexes, b1f, y1T, 4, 256, 129, statsAcc);
  ln_relu_kernel<<<4 * B_, 256, 0, stream>>>(y1T, statsAcc, 65536.f);

  // ---- layer 2: Cpad=512 (K=1536), in y1T, out y2T ----
  gemm_kernel<<<4 * B_, 256, 0, stream>>>(
      W2b, y1T, indexes, b2f, y2T, 4, 512, 129, statsAcc + 2 * B_);
  ln_relu_kernel<<<4 * B_, 256, 0, stream>>>(y2T, statsAcc + 2 * B_, 65536.f);

  // ---- layer 3 + gate + pool + head fused (emb stays in LDS) ----
  tail_kernel<<<B_, 256, 0, stream>>>(W3b, y2T, indexes, b3f,
                                      GW1b, gb1f, gw2f, gb2f,
                                      rw1f, rb1f, rw2f, rb2f, rw3f, rb3f,
                                      d_out, flagp);

  (void)in_sizes; (void)n_in; (void)out_size; (void)ws_size;
}

// Round 11
// 398.671 us; speedup vs baseline: 1.0367x; 1.0367x over previous
//
#include <hip/hip_runtime.h>
#include <stdint.h>

#define DI __device__ __forceinline__

static constexpr int B_   = 512;
static constexpr int N3_  = 381;

typedef short bf16x8 __attribute__((ext_vector_type(8)));
typedef float f32x4  __attribute__((ext_vector_type(4)));

DI float bf2f(uint32_t u) { union { uint32_t i; float f; } v; v.i = u << 16; return v.f; }
DI uint16_t f2bf(float f) {
  union { float f; uint32_t i; } v; v.f = f;
  uint32_t x = v.i;
  return (uint16_t)((x + 0x7fffu + ((x >> 16) & 1u)) >> 16);
}
DI void unpack8(uint4 u, float* v) {
  v[0] = bf2f(u.x & 0xffffu); v[1] = bf2f(u.x >> 16);
  v[2] = bf2f(u.y & 0xffffu); v[3] = bf2f(u.y >> 16);
  v[4] = bf2f(u.z & 0xffffu); v[5] = bf2f(u.z >> 16);
  v[6] = bf2f(u.w & 0xffffu); v[7] = bf2f(u.w >> 16);
}

DI void ldsload16(const uint16_t* g, uint16_t* l) {
  __builtin_amdgcn_global_load_lds((const __attribute__((address_space(1))) void*)g,
                                   (__attribute__((address_space(3))) void*)l,
                                   16, 0, 0);
}

// ---------------- fused prep: probe + transpose + all conversions ------------
struct PrepArgs {
  const void* trees; const void* w1; const void* w2; const void* w3; const void* gw1;
  const void* b1; const void* b2; const void* b3; const void* gb1;
  const void* gw2; const void* gb2;
  const void* rw1; const void* rb1; const void* rw2; const void* rb2;
  const void* rw3; const void* rb3;
  uint16_t* treesT; uint16_t* W1b; uint16_t* W2b; uint16_t* W3b; uint16_t* GW1b;
  float* b1f; float* b2f; float* b3f; float* gb1f; float* gw2f; float* gb2f;
  float* rw1f; float* rb1f; float* rw2f; float* rb2f; float* rw3f; float* rb3f;
  int* flagp; float* statsAcc;
};

static constexpr int PREP_TRANS_END = 3584;   // 7 * 512 transpose blocks
static constexpr int PREP_W1_END    = 3840;
static constexpr int PREP_W2_END    = 4352;
static constexpr int PREP_W3_END    = 4608;
static constexpr int PREP_GW1_END   = 4640;
static constexpr int PREP_F32_END   = 4672;

DI void wcvt_range(const void* src, uint16_t* dst, int O, int C, int Cpad,
                   int isf32, int idx, int nb) {
  int Kpad = 3 * Cpad;
  int n = O * Kpad;
  int stride = nb * 256;
  for (int i = idx * 256 + (int)threadIdx.x; i < n; i += stride) {
    int o = i / Kpad, e = i - o * Kpad;
    int reg = e / Cpad, c = e - reg * Cpad;
    uint16_t v = 0;
    if (c < C) {
      int s = (o * C + c) * 3 + reg;
      v = isf32 ? f2bf(((const float*)src)[s]) : ((const uint16_t*)src)[s];
    }
    dst[i] = v;
  }
}

DI void fcvt_range(const void* src, float* dst, int n, int isf32, int idx, int nb) {
  int stride = nb * 256;
  for (int i = idx * 256 + (int)threadIdx.x; i < n; i += stride)
    dst[i] = isf32 ? ((const float*)src)[i] : bf2f(((const uint16_t*)src)[i]);
}

__global__ __launch_bounds__(256)
void prep_kernel(PrepArgs a) {
  __shared__ int cnt;
  __shared__ uint16_t sX[32][130];

  const int id = blockIdx.x;
  const int tx = threadIdx.x;

  if (tx == 0) cnt = 0;
  __syncthreads();
  {
    const uint16_t* t16 = (const uint16_t*)a.trees;
    int local = 0;
    #pragma unroll
    for (int q = 0; q < 2; q++) {
      uint16_t u = t16[tx * 2 + q];
      int ex = (u >> 7) & 0xff;
      if (ex >= 110 && ex <= 133) local++;
    }
    atomicAdd(&cnt, local);
  }
  __syncthreads();
  const int isf32 = (cnt >= 450) ? 0 : 1;

  if (id == 0) {
    if (tx == 0) *a.flagp = isf32;
    #pragma unroll
    for (int q = 0; q < 8; q++) a.statsAcc[q * 256 + tx] = 0.f;
  }

  if (id < PREP_TRANS_END) {
    const int b = id / 7, c0 = (id % 7) * 32;
    const int cn = min(32, 200 - c0);
    if (isf32) {
      const float* src = (const float*)a.trees + ((size_t)b * 200 + c0) * 128;
      for (int t = tx; t < cn * 128; t += 256) {
        int c = t >> 7, m = t & 127;
        sX[c][m] = f2bf(src[c * 128 + m]);
      }
    } else {
      const uint32_t* src = (const uint32_t*)((const uint16_t*)a.trees + ((size_t)b * 200 + c0) * 128);
      for (int t = tx; t < cn * 64; t += 256) {
        int c = t >> 6, p = t & 63;
        ((uint32_t*)&sX[c][0])[p] = src[c * 64 + p];
      }
    }
    __syncthreads();
    uint32_t* out = (uint32_t*)(a.treesT + (size_t)b * 129 * 256 + c0);
    for (int p = tx; p < 129 * 16; p += 256) {
      int m = p >> 4, u = p & 15;
      int c = u * 2;
      uint32_t v = 0;
      if (m < 128) {
        uint16_t lo = (c     < cn) ? sX[c][m]     : (uint16_t)0;
        uint16_t hi = (c + 1 < cn) ? sX[c + 1][m] : (uint16_t)0;
        v = (uint32_t)lo | ((uint32_t)hi << 16);
      }
      out[(size_t)m * 128 + u] = v;
    }
  } else if (id < PREP_W1_END) {
    wcvt_range(a.w1, a.W1b, 512, 200, 256, isf32, id - PREP_TRANS_END, PREP_W1_END - PREP_TRANS_END);
  } else if (id < PREP_W2_END) {
    wcvt_range(a.w2, a.W2b, 512, 512, 512, isf32, id - PREP_W1_END, PREP_W2_END - PREP_W1_END);
  } else if (id < PREP_W3_END) {
    wcvt_range(a.w3, a.W3b, 256, 512, 512, isf32, id - PREP_W2_END, PREP_W3_END - PREP_W2_END);
  } else if (id < PREP_GW1_END) {
    int idx = id - PREP_W3_END, nb = PREP_GW1_END - PREP_W3_END;
    int stride = nb * 256;
    for (int i = idx * 256 + tx; i < 128 * 256; i += stride)
      a.GW1b[i] = isf32 ? f2bf(((const float*)a.gw1)[i]) : ((const uint16_t*)a.gw1)[i];
  } else {
    int idx = id - PREP_GW1_END, nb = PREP_F32_END - PREP_GW1_END;
    fcvt_range(a.rw1, a.rw1f, 128 * 512, isf32, idx, nb);
    fcvt_range(a.rw2, a.rw2f, 64 * 128, isf32, idx, nb);
    if (idx == 0) {
      fcvt_range(a.b1, a.b1f, 512, isf32, 0, 1);
      fcvt_range(a.b2, a.b2f, 512, isf32, 0, 1);
      fcvt_range(a.b3, a.b3f, 256, isf32, 0, 1);
      fcvt_range(a.gb1, a.gb1f, 128, isf32, 0, 1);
      fcvt_range(a.gw2, a.gw2f, 128, isf32, 0, 1);
      fcvt_range(a.gb2, a.gb2f, 1, isf32, 0, 1);
      fcvt_range(a.rb1, a.rb1f, 128, isf32, 0, 1);
      fcvt_range(a.rb2, a.rb2f, 64, isf32, 0, 1);
      fcvt_range(a.rw3, a.rw3f, 64, isf32, 0, 1);
      fcvt_range(a.rb3, a.rb3f, 1, isf32, 0, 1);
    }
  }
}

// ------ gemm variant A (layer 1): 128j x 256o tile, 2 blocks/CU -------------
// Short-K regime: fewer blocks -> less per-block prologue/epilogue overhead.
__global__ __launch_bounds__(256, 2)
void gemm256_kernel(const uint16_t* __restrict__ A,
                    const uint16_t* __restrict__ xT,
                    const int* __restrict__ idxg,
                    const float* __restrict__ bias,
                    uint16_t* __restrict__ Y,
                    int nO, int Cpad, int outRS,
                    float* __restrict__ statsAcc) {
  __shared__ __align__(16) uint16_t sA[256 * 64];
  __shared__ __align__(16) uint16_t sB[128 * 64];
  __shared__ float sBias[256];
  __shared__ int sIdx[384];
  __shared__ float2 sRed[256];

  const int id   = blockIdx.x;
  const int xcd  = id & 7;
  const int rest = id >> 3;
  const int ot   = rest % nO;
  const int b    = (rest / nO) * 8 + xcd;
  const int obase = ot * 256;
  const int O     = nO * 256;

  const int tx    = threadIdx.x;
  const int wave  = tx >> 6, lane = tx & 63;
  const int wj    = wave & 1, wo = wave >> 1;
  const int Kpad  = 3 * Cpad;

  for (int t = tx; t < N3_; t += 256) sIdx[t] = idxg[(size_t)b * N3_ + t];
  sBias[tx] = bias[obase + tx];
  __syncthreads();

  const uint16_t* Abase = A + (size_t)obase * Kpad;
  const uint16_t* Bbase = xT + (size_t)b * 129 * Cpad;

  const int srow = lane >> 3;
  const int schk = lane & 7;
  const int lm = lane & 15;
  const int kg = lane >> 4;

  f32x4 zero4 = {0.f, 0.f, 0.f, 0.f};
  f32x4 acc[4][8];
  #pragma unroll
  for (int i = 0; i < 4; i++)
    #pragma unroll
    for (int j = 0; j < 8; j++) acc[i][j] = zero4;

  for (int reg = 0; reg < 3; reg++) {
    int ridx[4];
    #pragma unroll
    for (int i = 0; i < 4; i++) {
      int r = i * 32 + wave * 8 + srow;
      ridx[i] = (r == 0) ? 128 : sIdx[3 * (r - 1) + reg];
    }
    for (int co = 0; co < Cpad; co += 64) {
      __syncthreads();
      #pragma unroll
      for (int i = 0; i < 8; i++) {
        int r  = i * 32 + wave * 8 + srow;
        int ca = schk ^ (r & 7);
        ldsload16(Abase + (size_t)r * Kpad + reg * Cpad + co + ca * 8,
                  &sA[(i * 32 + wave * 8) * 64]);
      }
      #pragma unroll
      for (int i = 0; i < 4; i++) {
        int r  = i * 32 + wave * 8 + srow;
        int ca = schk ^ (r & 7);
        ldsload16(Bbase + (size_t)ridx[i] * Cpad + co + ca * 8,
                  &sB[(i * 32 + wave * 8) * 64]);
      }
      __syncthreads();
      #pragma unroll
      for (int s = 0; s < 2; s++) {
        bf16x8 xv[4], wv[8];
        #pragma unroll
        for (int f = 0; f < 4; f++) {
          int rj = wj * 64 + f * 16 + lm;
          int cj = (s * 4 + kg) ^ (rj & 7);
          xv[f] = *(const bf16x8*)&sB[rj * 64 + cj * 8];
        }
        #pragma unroll
        for (int f = 0; f < 8; f++) {
          int ro = wo * 128 + f * 16 + lm;
          int cw = (s * 4 + kg) ^ (ro & 7);
          wv[f] = *(const bf16x8*)&sA[ro * 64 + cw * 8];
        }
        #pragma unroll
        for (int fj = 0; fj < 4; fj++)
          #pragma unroll
          for (int fo = 0; fo < 8; fo++)
            acc[fj][fo] = __builtin_amdgcn_mfma_f32_16x16x32_bf16(xv[fj], wv[fo], acc[fj][fo], 0, 0, 0);
      }
    }
  }

  float s1 = 0.f, s2 = 0.f;
  #pragma unroll
  for (int fj = 0; fj < 4; fj++) {
    #pragma unroll
    for (int fo = 0; fo < 8; fo++) {
      int olocal = wo * 128 + fo * 16 + lm;
      float bo = sBias[olocal];
      #pragma unroll
      for (int r = 0; r < 4; r++) {
        int j = wj * 64 + fj * 16 + kg * 4 + r;
        float v = acc[fj][fo][r] + bo;
        if (j == 0) v = 0.f;
        s1 += v; s2 += v * v;
        Y[((size_t)b * outRS + j) * O + obase + olocal] = f2bf(v);
      }
    }
  }

  sRed[tx] = make_float2(s1, s2);
  __syncthreads();
  for (int s = 128; s > 0; s >>= 1) {
    if (tx < s) { sRed[tx].x += sRed[tx + s].x; sRed[tx].y += sRed[tx + s].y; }
    __syncthreads();
  }
  if (tx == 0) {
    atomicAdd(&statsAcc[b * 2],     sRed[0].x);
    atomicAdd(&statsAcc[b * 2 + 1], sRed[0].y);
  }
}

// ------ gemm variant B (layer 2): 128x128 tile, 4 blocks/CU -----------------
// Long-K regime: occupancy hides staging latency.
__global__ __launch_bounds__(256, 4)
void gemm128_kernel(const uint16_t* __restrict__ A,
                    const uint16_t* __restrict__ xT,
                    const int* __restrict__ idxg,
                    const float* __restrict__ bias,
                    uint16_t* __restrict__ Y,
                    int nO, int Cpad, int outRS,
                    float* __restrict__ statsAcc) {
  __shared__ __align__(16) uint16_t sA[128 * 64];
  __shared__ __align__(16) uint16_t sB[128 * 64];
  __shared__ float sBias[128];
  __shared__ int sIdx[384];
  __shared__ float2 sRed[256];

  const int id   = blockIdx.x;
  const int xcd  = id & 7;
  const int rest = id >> 3;
  const int ot   = rest % nO;
  const int b    = (rest / nO) * 8 + xcd;
  const int obase = ot * 128;
  const int O     = nO * 128;

  const int tx    = threadIdx.x;
  const int wave  = tx >> 6, lane = tx & 63;
  const int wj    = wave & 1, wo = wave >> 1;
  const int Kpad  = 3 * Cpad;

  for (int t = tx; t < N3_; t += 256) sIdx[t] = idxg[(size_t)b * N3_ + t];
  if (tx < 128) sBias[tx] = bias[obase + tx];
  __syncthreads();

  const uint16_t* Abase = A + (size_t)obase * Kpad;
  const uint16_t* Bbase = xT + (size_t)b * 129 * Cpad;

  const int srow = lane >> 3;
  const int schk = lane & 7;
  const int lm = lane & 15;
  const int kg = lane >> 4;

  f32x4 zero4 = {0.f, 0.f, 0.f, 0.f};
  f32x4 acc[4][4];
  #pragma unroll
  for (int i = 0; i < 4; i++)
    #pragma unroll
    for (int j = 0; j < 4; j++) acc[i][j] = zero4;

  for (int reg = 0; reg < 3; reg++) {
    int ridx[4];
    #pragma unroll
    for (int i = 0; i < 4; i++) {
      int r = wave * 8 + i * 32 + srow;
      ridx[i] = (r == 0) ? 128 : sIdx[3 * (r - 1) + reg];
    }
    for (int co = 0; co < Cpad; co += 64) {
      __syncthreads();
      #pragma unroll
      for (int i = 0; i < 4; i++) {
        int r  = wave * 8 + i * 32 + srow;
        int ca = schk ^ (r & 7);
        ldsload16(Abase + (size_t)r * Kpad + reg * Cpad + co + ca * 8,
                  &sA[(wave * 8 + i * 32) * 64]);
        ldsload16(Bbase + (size_t)ridx[i] * Cpad + co + ca * 8,
                  &sB[(wave * 8 + i * 32) * 64]);
      }
      __syncthreads();
      #pragma unroll
      for (int s = 0; s < 2; s++) {
        bf16x8 xv[4], wv[4];
        #pragma unroll
        for (int f = 0; f < 4; f++) {
          int rj = wj * 64 + f * 16 + lm;
          int cj = (s * 4 + kg) ^ (rj & 7);
          xv[f] = *(const bf16x8*)&sB[rj * 64 + cj * 8];
          int ro = wo * 64 + f * 16 + lm;
          int cw = (s * 4 + kg) ^ (ro & 7);
          wv[f] = *(const bf16x8*)&sA[ro * 64 + cw * 8];
        }
        #pragma unroll
        for (int fj = 0; fj < 4; fj++)
          #pragma unroll
          for (int fo = 0; fo < 4; fo++)
            acc[fj][fo] = __builtin_amdgcn_mfma_f32_16x16x32_bf16(xv[fj], wv[fo], acc[fj][fo], 0, 0, 0);
      }
    }
  }

  float s1 = 0.f, s2 = 0.f;
  #pragma unroll
  for (int fj = 0; fj < 4; fj++) {
    #pragma unroll
    for (int fo = 0; fo < 4; fo++) {
      int olocal = wo * 64 + fo * 16 + lm;
      float bo = sBias[olocal];
      #pragma unroll
      for (int r = 0; r < 4; r++) {
        int j = wj * 64 + fj * 16 + kg * 4 + r;
        float v = acc[fj][fo][r] + bo;
        if (j == 0) v = 0.f;
        s1 += v; s2 += v * v;
        Y[((size_t)b * outRS + j) * O + obase + olocal] = f2bf(v);
      }
    }
  }

  sRed[tx] = make_float2(s1, s2);
  __syncthreads();
  for (int s = 128; s > 0; s >>= 1) {
    if (tx < s) { sRed[tx].x += sRed[tx + s].x; sRed[tx].y += sRed[tx + s].y; }
    __syncthreads();
  }
  if (tx == 0) {
    atomicAdd(&statsAcc[b * 2],     sRed[0].x);
    atomicAdd(&statsAcc[b * 2 + 1], sRed[0].y);
  }
}

// ------- LN+ReLU in place on yT [B][129][512]; b from blockIdx --------------
__global__ __launch_bounds__(256)
void ln_relu_kernel(uint16_t* __restrict__ y, const float* __restrict__ statsAcc,
                    float count) {
  const int b    = blockIdx.x >> 2;
  const int part = blockIdx.x & 3;
  float s = statsAcc[b * 2], ss = statsAcc[b * 2 + 1];
  float mean = s / count;
  float var = fmaxf((ss - s * s / count) / (count - 1.0f), 0.f);
  float scale = 1.0f / (sqrtf(var) + 1e-5f);

  uint4* yb = (uint4*)y + (size_t)b * 8256;       // 129*64 uint4 per batch
  for (int i = part * 2064 + threadIdx.x; i < (part + 1) * 2064; i += 256) {
    int r = i >> 6;
    uint4 out;
    if (r == 128) {
      out = make_uint4(0, 0, 0, 0);
    } else {
      uint4 u = yb[i];
      float v[8]; unpack8(u, v);
      uint32_t rr[4];
      #pragma unroll
      for (int k = 0; k < 4; k++) {
        float a  = fmaxf((v[2 * k]     - mean) * scale, 0.f);
        float bb = fmaxf((v[2 * k + 1] - mean) * scale, 0.f);
        rr[k] = (uint32_t)f2bf(a) | ((uint32_t)f2bf(bb) << 16);
      }
      out = make_uint4(rr[0], rr[1], rr[2], rr[3]);
    }
    yb[i] = out;
  }
}

// ------ tail: layer-3 gemm (emb stays in LDS) + gate + softmax + pool + head
__global__ __launch_bounds__(256, 2)
void tail_kernel(const uint16_t* __restrict__ W3,      // [256][1536]
                 const uint16_t* __restrict__ xT,      // y2T [B][129][512]
                 const int* __restrict__ idxg,
                 const float* __restrict__ b3,
                 const uint16_t* __restrict__ gw1b,    // [128][256] bf16
                 const float* __restrict__ gb1,
                 const float* __restrict__ gw2, const float* __restrict__ gb2,
                 const float* __restrict__ rw1, const float* __restrict__ rb1,
                 const float* __restrict__ rw2, const float* __restrict__ rb2,
                 const float* __restrict__ rw3, const float* __restrict__ rb3,
                 void* __restrict__ dout, const int* __restrict__ flag) {
  __shared__ __align__(16) uint16_t sEmbF[4][128][64];   // 64 KB; aliases sA/sB
  __shared__ float sBias[256];
  __shared__ int sIdx[384];
  __shared__ float sRedG[4][128];
  __shared__ float sSm[128];
  __shared__ float sAttn[128];
  __shared__ float sPool4[4 * 256];
  __shared__ __align__(16) float sC[512];
  __shared__ __align__(16) float sH1[128];
  __shared__ float sH2[64];

  uint16_t* sA = &sEmbF[0][0][0];          // 256*64 shorts = 32 KB
  uint16_t* sB = sA + 256 * 64;            // 128*64 shorts = 16 KB

  const int b  = blockIdx.x;
  const int tx = threadIdx.x;
  const int wave = tx >> 6, lane = tx & 63;
  const int wj = wave & 1, wo = wave >> 1;
  const int lm = lane & 15, kg = lane >> 4;
  const int srow = lane >> 3, schk = lane & 7;
  const int Kpad = 1536, Cpad = 512;

  for (int t = tx; t < N3_; t += 256) sIdx[t] = idxg[(size_t)b * N3_ + t];
  sBias[tx] = b3[tx];
  __syncthreads();

  const uint16_t* Bbase = xT + (size_t)b * 129 * Cpad;

  // ---- phase 1: layer-3 GEMM (128j x 256o), acc in regs ----
  f32x4 zero4 = {0.f, 0.f, 0.f, 0.f};
  f32x4 acc[4][8];
  #pragma unroll
  for (int i = 0; i < 4; i++)
    #pragma unroll
    for (int j = 0; j < 8; j++) acc[i][j] = zero4;

  for (int reg = 0; reg < 3; reg++) {
    int ridx[4];
    #pragma unroll
    for (int i = 0; i < 4; i++) {
      int r = i * 32 + wave * 8 + srow;
      ridx[i] = (r == 0) ? 128 : sIdx[3 * (r - 1) + reg];
    }
    for (int co = 0; co < Cpad; co += 64) {
      __syncthreads();
      #pragma unroll
      for (int i = 0; i < 8; i++) {
        int r  = i * 32 + wave * 8 + srow;
        int ca = schk ^ (r & 7);
        ldsload16(W3 + (size_t)r * Kpad + reg * Cpad + co + ca * 8,
                  &sA[(i * 32 + wave * 8) * 64]);
      }
      #pragma unroll
      for (int i = 0; i < 4; i++) {
        int r  = i * 32 + wave * 8 + srow;
        int ca = schk ^ (r & 7);
        ldsload16(Bbase + (size_t)ridx[i] * Cpad + co + ca * 8,
                  &sB[(i * 32 + wave * 8) * 64]);
      }
      __syncthreads();
      #pragma unroll
      for (int s = 0; s < 2; s++) {
        bf16x8 xv[4], wv[8];
        #pragma unroll
        for (int f = 0; f < 4; f++) {
          int rj = wj * 64 + f * 16 + lm;
          int cj = (s * 4 + kg) ^ (rj & 7);
          xv[f] = *(const bf16x8*)&sB[rj * 64 + cj * 8];
        }
        #pragma unroll
        for (int f = 0; f < 8; f++) {
          int ro = wo * 128 + f * 16 + lm;
          int cw = (s * 4 + kg) ^ (ro & 7);
          wv[f] = *(const bf16x8*)&sA[ro * 64 + cw * 8];
        }
        #pragma unroll
        for (int fj = 0; fj < 4; fj++)
          #pragma unroll
          for (int fo = 0; fo < 8; fo++)
            acc[fj][fo] = __builtin_amdgcn_mfma_f32_16x16x32_bf16(xv[fj], wv[fo], acc[fj][fo], 0, 0, 0);
      }
    }
  }

  // ---- phase 2: epilogue -> LDS emb in swizzled layout ----
  __syncthreads();   // sA/sB dead; reuse as sEmbF
  #pragma unroll
  for (int fj = 0; fj < 4; fj++) {
    #pragma unroll
    for (int fo = 0; fo < 8; fo++) {
      int olocal = wo * 128 + fo * 16 + lm;
      int sec = olocal >> 6, oc = olocal & 63;
      float bo = sBias[olocal];
      #pragma unroll
      for (int r = 0; r < 4; r++) {
        int j = wj * 64 + fj * 16 + kg * 4 + r;
        float v = acc[fj][fo][r] + bo;
        if (j == 0) v = 0.f;
        int chunk = (oc >> 3) ^ (j & 7);
        sEmbF[sec][j][chunk * 8 + (oc & 7)] = f2bf(v);
      }
    }
  }
  __syncthreads();

  // ---- phase 3: gate1 MFMA from LDS emb ----
  const int h0 = wave * 32;
  f32x4 acc2[2][8];
  #pragma unroll
  for (int i = 0; i < 2; i++)
    #pragma unroll
    for (int t = 0; t < 8; t++) acc2[i][t] = zero4;

  #pragma unroll
  for (int s4 = 0; s4 < 4; s4++) {
    #pragma unroll
    for (int s = 0; s < 2; s++) {
      bf16x8 a0 = *(const bf16x8*)(gw1b + (size_t)(h0 + lm) * 256 + s4 * 64 + s * 32 + kg * 8);
      bf16x8 a1 = *(const bf16x8*)(gw1b + (size_t)(h0 + 16 + lm) * 256 + s4 * 64 + s * 32 + kg * 8);
      #pragma unroll
      for (int t = 0; t < 8; t++) {
        int rn = t * 16 + lm;
        int cn = (s * 4 + kg) ^ (rn & 7);
        bf16x8 bv = *(const bf16x8*)&sEmbF[s4][rn][cn * 8];
        acc2[0][t] = __builtin_amdgcn_mfma_f32_16x16x32_bf16(a0, bv, acc2[0][t], 0, 0, 0);
        acc2[1][t] = __builtin_amdgcn_mfma_f32_16x16x32_bf16(a1, bv, acc2[1][t], 0, 0, 0);
      }
    }
  }

  float gb[2][4], gv[2][4];
  #pragma unroll
  for (int ht = 0; ht < 2; ht++)
    #pragma unroll
    for (int r = 0; r < 4; r++) {
      int h = h0 + ht * 16 + kg * 4 + r;
      gb[ht][r] = gb1[h]; gv[ht][r] = gw2[h];
    }
  float p[8];
  #pragma unroll
  for (int t = 0; t < 8; t++) {
    float s = 0.f;
    #pragma unroll
    for (int ht = 0; ht < 2; ht++)
      #pragma unroll
      for (int r = 0; r < 4; r++)
        s += fmaxf(acc2[ht][t][r] + gb[ht][r], 0.f) * gv[ht][r];
    s += __shfl_xor(s, 16);
    s += __shfl_xor(s, 32);
    p[t] = s;
  }
  if (lane < 16) {
    #pragma unroll
    for (int t = 0; t < 8; t++) sRedG[wave][t * 16 + lane] = p[t];
  }
  __syncthreads();

  // ---- softmax over m ----
  float e = 0.f;
  if (tx < 128) {
    float v = sRedG[0][tx] + sRedG[1][tx] + sRedG[2][tx] + sRedG[3][tx] + gb2[0];
    sSm[tx] = v;
    sAttn[tx] = v;
  }
  __syncthreads();
  for (int s = 64; s > 0; s >>= 1) {
    if (tx < s) sSm[tx] = fmaxf(sSm[tx], sSm[tx + s]);
    __syncthreads();
  }
  float mx = sSm[0];
  __syncthreads();
  if (tx < 128) { e = expf(sAttn[tx] - mx); sSm[tx] = e; }
  __syncthreads();
  for (int s = 64; s > 0; s >>= 1) {
    if (tx < s) sSm[tx] += sSm[tx + s];
    __syncthreads();
  }
  float denom = sSm[0];
  __syncthreads();
  if (tx < 128) sAttn[tx] = e / denom;
  __syncthreads();

  // ---- pool from LDS emb: wave covers 32 m rows; lane -> f pairs ----
  {
    const int f0 = 2 * lane;           // 0..126
    const int sec0 = f0 >> 6, oc0 = f0 & 63;
    const int sec2 = sec0 + 2;         // f+128
    float pl00 = 0.f, pl01 = 0.f, pl10 = 0.f, pl11 = 0.f;
    const int mw = wave * 32;
    for (int mi = 0; mi < 32; mi++) {
      int m = mw + mi;
      float a = sAttn[m];
      int idx = ((oc0 >> 3) ^ (m & 7)) * 8 + (oc0 & 7);
      uint32_t u0 = *(const uint32_t*)&sEmbF[sec0][m][idx];
      uint32_t u1 = *(const uint32_t*)&sEmbF[sec2][m][idx];
      pl00 = fmaf(a, bf2f(u0 & 0xffffu), pl00);
      pl01 = fmaf(a, bf2f(u0 >> 16),     pl01);
      pl10 = fmaf(a, bf2f(u1 & 0xffffu), pl10);
      pl11 = fmaf(a, bf2f(u1 >> 16),     pl11);
    }
    sPool4[wave * 256 + lane * 2]           = pl00;
    sPool4[wave * 256 + lane * 2 + 1]       = pl01;
    sPool4[wave * 256 + 128 + lane * 2]     = pl10;
    sPool4[wave * 256 + 128 + lane * 2 + 1] = pl11;
  }
  __syncthreads();

  float pool = sPool4[tx] + sPool4[256 + tx] + sPool4[512 + tx] + sPool4[768 + tx];
  float root;
  {
    int sec = tx >> 6, oc = tx & 63;
    int idx = ((oc >> 3) ^ 1) * 8 + (oc & 7);
    root = bf2f(sEmbF[sec][1][idx]);
  }
  sC[tx]       = root;
  sC[256 + tx] = pool;

  const int isf32 = (*flag != 0);
  if (!isf32) {
    uint16_t* o = ((uint16_t*)dout) + 512;
    o[b * 512 + tx]       = f2bf(root);
    o[b * 512 + 256 + tx] = f2bf(pool);
  } else {
    float* o = ((float*)dout) + 512;
    o[b * 512 + tx]       = root;
    o[b * 512 + 256 + tx] = pool;
  }
  __syncthreads();

  // ---- fused MLP head ----
  if (tx < 128) {
    float a = rb1[tx];
    const float4* wr = (const float4*)(rw1 + (size_t)tx * 512);
    for (int i = 0; i < 128; i++) {
      float4 w4 = wr[i];
      float4 c4 = *(const float4*)&sC[i * 4];
      a = fmaf(w4.x, c4.x, a); a = fmaf(w4.y, c4.y, a);
      a = fmaf(w4.z, c4.z, a); a = fmaf(w4.w, c4.w, a);
    }
    sH1[tx] = fmaxf(a, 0.f);
  }
  __syncthreads();
  if (tx < 64) {
    float a2 = rb2[tx];
    const float4* wr2 = (const float4*)(rw2 + (size_t)tx * 128);
    for (int i = 0; i < 32; i++) {
      float4 w4 = wr2[i];
      float4 h4 = *(const float4*)&sH1[i * 4];
      a2 = fmaf(w4.x, h4.x, a2); a2 = fmaf(w4.y, h4.y, a2);
      a2 = fmaf(w4.z, h4.z, a2); a2 = fmaf(w4.w, h4.w, a2);
    }
    sH2[tx] = fmaxf(a2, 0.f);
  }
  __syncthreads();
  if (tx < 64) {
    float pv = sH2[tx] * rw3[tx];
    for (int off = 32; off > 0; off >>= 1) pv += __shfl_down(pv, off);
    if (tx == 0) {
      float o = pv + rb3[0];
      if (!isf32) ((uint16_t*)dout)[b] = f2bf(o);
      else        ((float*)dout)[b]    = o;
    }
  }
}

// ---------------- launch -----------------------------------------------------
extern "C" void kernel_launch(void* const* d_in, const int* in_sizes, int n_in,
                              void* d_out, int out_size, void* d_ws, size_t ws_size,
                              hipStream_t stream) {
  const void* trees   = d_in[0];
  const int*  indexes = (const int*)d_in[1];

  char* ws = (char*)d_ws;
  size_t off = 0;
  auto alloc = [&](size_t bytes) -> char* {
    char* p = ws + off;
    off += (bytes + 255) & ~(size_t)255;
    return p;
  };

  int*   flagp    = (int*)alloc(256);
  float* statsAcc = (float*)alloc(4 * B_ * sizeof(float));
  float* b1f = (float*)alloc(512 * 4);
  float* b2f = (float*)alloc(512 * 4);
  float* b3f = (float*)alloc(256 * 4);
  float* gb1f = (float*)alloc(128 * 4);
  float* gw2f = (float*)alloc(128 * 4);
  float* gb2f = (float*)alloc(4);
  float* rw1f = (float*)alloc(128 * 512 * 4);
  float* rb1f = (float*)alloc(128 * 4);
  float* rw2f = (float*)alloc(64 * 128 * 4);
  float* rb2f = (float*)alloc(64 * 4);
  float* rw3f = (float*)alloc(64 * 4);
  float* rb3f = (float*)alloc(4);
  uint16_t* W1b  = (uint16_t*)alloc((size_t)512 * 768 * 2);
  uint16_t* W2b  = (uint16_t*)alloc((size_t)512 * 1536 * 2);
  uint16_t* W3b  = (uint16_t*)alloc((size_t)256 * 1536 * 2);
  uint16_t* GW1b = (uint16_t*)alloc((size_t)128 * 256 * 2);
  uint16_t* bufA = (uint16_t*)alloc((size_t)B_ * 129 * 512 * 2);   // y1T
  uint16_t* bufB = (uint16_t*)alloc((size_t)B_ * 129 * 512 * 2);   // treesT, later y2T

  uint16_t* treesT = bufB;            // [B][129][256]
  uint16_t* y1T    = bufA;            // [B][129][512]
  uint16_t* y2T    = bufB;            // [B][129][512]

  PrepArgs pa;
  pa.trees = trees;
  pa.w1 = d_in[2];  pa.b1 = d_in[3];
  pa.w2 = d_in[4];  pa.b2 = d_in[5];
  pa.w3 = d_in[6];  pa.b3 = d_in[7];
  pa.gw1 = d_in[8]; pa.gb1 = d_in[9];
  pa.gw2 = d_in[10]; pa.gb2 = d_in[11];
  pa.rw1 = d_in[12]; pa.rb1 = d_in[13];
  pa.rw2 = d_in[14]; pa.rb2 = d_in[15];
  pa.rw3 = d_in[16]; pa.rb3 = d_in[17];
  pa.treesT = treesT; pa.W1b = W1b; pa.W2b = W2b; pa.W3b = W3b; pa.GW1b = GW1b;
  pa.b1f = b1f; pa.b2f = b2f; pa.b3f = b3f; pa.gb1f = gb1f; pa.gw2f = gw2f; pa.gb2f = gb2f;
  pa.rw1f = rw1f; pa.rb1f = rb1f; pa.rw2f = rw2f; pa.rb2f = rb2f; pa.rw3f = rw3f; pa.rb3f = rb3f;
  pa.flagp = flagp; pa.statsAcc = statsAcc;

  prep_kernel<<<PREP_F32_END, 256, 0, stream>>>(pa);

  // ---- layer 1: Cpad=256 (K=768), 256-o tile (overhead-bound regime) ----
  gemm256_kernel<<<2 * B_, 256, 0, stream>>>(
      W1b, treesT, indexes, b1f, y1T, 2, 256, 129, statsAcc);
  ln_relu_kernel<<<4 * B_, 256, 0, stream>>>(y1T, statsAcc, 65536.f);

  // ---- layer 2: Cpad=512 (K=1536), 128-o tile (occupancy-bound regime) ----
  gemm128_kernel<<<4 * B_, 256, 0, stream>>>(
      W2b, y1T, indexes, b2f, y2T, 4, 512, 129, statsAcc + 2 * B_);
  ln_relu_kernel<<<4 * B_, 256, 0, stream>>>(y2T, statsAcc + 2 * B_, 65536.f);

  // ---- layer 3 + gate + pool + head fused (emb stays in LDS) ----
  tail_kernel<<<B_, 256, 0, stream>>>(W3b, y2T, indexes, b3f,
                                      GW1b, gb1f, gw2f, gb2f,
                                      rw1f, rb1f, rw2f, rb2f, rw3f, rb3f,
                                      d_out, flagp);

  (void)in_sizes; (void)n_in; (void)out_size; (void)ws_size;
}